// Round 1
// baseline (765.800 us; speedup 1.0000x reference)
//
#include <hip/hip_runtime.h>

#define N_EDGES 3200000
#define N_NODES 100000

typedef __attribute__((ext_vector_type(8))) short bf16x8;  // 8 bf16 in 4 VGPRs
typedef __attribute__((ext_vector_type(4))) float f32x4;

// ---------- bf16 helpers ----------
__device__ inline unsigned short f2bf(float f) {
    unsigned u = __float_as_uint(f);
    u += 0x7fffu + ((u >> 16) & 1u);       // round-to-nearest-even
    return (unsigned short)(u >> 16);
}
__device__ inline unsigned pack_bf2(float lo, float hi) {
    return (unsigned)f2bf(lo) | ((unsigned)f2bf(hi) << 16);
}
__device__ inline float bflo(unsigned u) { return __uint_as_float(u << 16); }
__device__ inline float bfhi(unsigned u) { return __uint_as_float(u & 0xffff0000u); }

// ---------- pass 1: per-node projections + output zeroing + Wn2^T + cnt zero ----------
__global__ void __launch_bounds__(256) mpn_precompute(
    const float* __restrict__ x_node,
    const float* __restrict__ We1, const float* __restrict__ be1,
    const float* __restrict__ Wn1, const float* __restrict__ bn1,
    const float* __restrict__ Wn2,
    unsigned* __restrict__ Pd, unsigned* __restrict__ Ps,
    short* __restrict__ Wn2T,            // [32][64] bf16
    float* __restrict__ nm_out,          // zeroed here (poisoned by harness)
    int* __restrict__ cnt)               // per-dst degree counters (binned mode)
{
    const int n = blockIdx.x * 256 + threadIdx.x;
    if (n >= N_NODES) return;

    if (cnt) cnt[n] = 0;

    // zero the output region (needed for atomic fallback; harmless otherwise)
    {
        float4 z = make_float4(0.f, 0.f, 0.f, 0.f);
        float4* o = (float4*)(nm_out + (size_t)n * 32);
        #pragma unroll
        for (int i = 0; i < 8; ++i) o[i] = z;
    }
    // transpose Wn2 [64][32] -> Wn2T [32][64] bf16 (first 2048 threads)
    if (n < 2048) Wn2T[n] = (short)f2bf(Wn2[(n & 63) * 32 + (n >> 6)]);

    float x[32];
    {
        const float4* px = (const float4*)(x_node + (size_t)n * 32);
        #pragma unroll
        for (int i = 0; i < 8; ++i) {
            float4 v = px[i];
            x[4*i+0] = v.x; x[4*i+1] = v.y; x[4*i+2] = v.z; x[4*i+3] = v.w;
        }
    }

    float p1[32];
    #pragma unroll
    for (int j = 0; j < 32; ++j) p1[j] = be1[j];
    for (int k = 0; k < 32; ++k) {
        const float a = x[k];
        const float* w = We1 + k * 32;
        #pragma unroll
        for (int j = 0; j < 32; ++j) p1[j] = fmaf(a, w[j], p1[j]);
    }
    unsigned* pd = Pd + (size_t)n * 48;
    #pragma unroll
    for (int i = 0; i < 16; ++i) pd[i] = pack_bf2(p1[2*i], p1[2*i+1]);

    float p3[64];
    #pragma unroll
    for (int j = 0; j < 64; ++j) p3[j] = bn1[j];
    for (int k = 0; k < 32; ++k) {
        const float a = x[k];
        const float* w = Wn1 + k * 64;
        #pragma unroll
        for (int j = 0; j < 64; ++j) p3[j] = fmaf(a, w[j], p3[j]);
    }
    #pragma unroll
    for (int i = 0; i < 32; ++i) pd[16 + i] = pack_bf2(p3[2*i], p3[2*i+1]);

    float p2[32];
    #pragma unroll
    for (int j = 0; j < 32; ++j) p2[j] = 0.0f;
    for (int k = 0; k < 32; ++k) {
        const float a = x[k];
        const float* w = We1 + (32 + k) * 32;
        #pragma unroll
        for (int j = 0; j < 32; ++j) p2[j] = fmaf(a, w[j], p2[j]);
    }
    unsigned* ps = Ps + (size_t)n * 16;
    #pragma unroll
    for (int i = 0; i < 16; ++i) ps[i] = pack_bf2(p2[2*i], p2[2*i+1]);
}

// ---------- CSR build: histogram + block scan + fixup ----------
__global__ void __launch_bounds__(256) k_hist(const int* __restrict__ dst,
                                              int* __restrict__ cnt) {
    const int e = blockIdx.x * 256 + threadIdx.x;
    atomicAdd(cnt + dst[e], 1);
}

__global__ void __launch_bounds__(1024) k_scan_a(const int* __restrict__ cnt,
                                                 int* __restrict__ off,
                                                 int* __restrict__ blksum) {
    __shared__ int sh[1024];
    const int tid = threadIdx.x;
    const int i = blockIdx.x * 1024 + tid;
    int v = (i < N_NODES) ? cnt[i] : 0;
    sh[tid] = v;
    __syncthreads();
    for (int ofs = 1; ofs < 1024; ofs <<= 1) {
        int t = (tid >= ofs) ? sh[tid - ofs] : 0;
        __syncthreads();
        sh[tid] += t;
        __syncthreads();
    }
    if (i < N_NODES) off[i] = sh[tid] - v;         // block-local exclusive
    if (tid == 1023) blksum[blockIdx.x] = sh[1023];
}

__global__ void __launch_bounds__(128) k_scan_b(int* __restrict__ blksum, int nblk) {
    __shared__ int sh[128];
    const int tid = threadIdx.x;
    int v = (tid < nblk) ? blksum[tid] : 0;
    sh[tid] = v;
    __syncthreads();
    for (int ofs = 1; ofs < 128; ofs <<= 1) {
        int t = (tid >= ofs) ? sh[tid - ofs] : 0;
        __syncthreads();
        sh[tid] += t;
        __syncthreads();
    }
    if (tid < nblk) blksum[tid] = sh[tid] - v;     // exclusive block offsets
}

__global__ void __launch_bounds__(1024) k_scan_c(int* __restrict__ off,
                                                 int* __restrict__ cursor,
                                                 const int* __restrict__ blksum) {
    const int i = blockIdx.x * 1024 + threadIdx.x;
    if (i == 0) off[N_NODES] = N_EDGES;
    if (i < N_NODES) {
        const int o = off[i] + blksum[blockIdx.x];
        off[i] = o;
        cursor[i] = o;
    }
}

// ---------- pass 2: per-edge MLPs (h2@Wn2 via MFMA) ----------
// msg32 != null: write bf16 message row to binned slot (1 atomic/edge).
// msg32 == null: legacy coalesced-atomic segment-sum (fallback).
__global__ void __launch_bounds__(256) mpn_main(
    const unsigned* __restrict__ Pd,
    const unsigned* __restrict__ Ps,
    const float* __restrict__ x_edge,
    const int* __restrict__ src,
    const int* __restrict__ dst,
    const float* __restrict__ We1,  // rows 64..69
    const float* __restrict__ We2, const float* __restrict__ be2,
    const float* __restrict__ Wn1,  // rows 32..37
    const short* __restrict__ Wn2T, // [32][64] bf16
    const float* __restrict__ bn2,
    float* __restrict__ nm_out,     // [N_NODES, 32] (fallback only)
    float* __restrict__ em_out,     // [N_EDGES, 6]
    unsigned* __restrict__ msg32,   // [N_EDGES][16] packed bf16x2, binned
    int* __restrict__ cursor)       // [N_NODES] slot cursors
{
    __shared__ unsigned s_h2[4][64][36];   // 36864 B
    __shared__ int      s_dst[128];

    const int tid  = threadIdx.x;
    const int lane = tid & 63;
    const int wave = tid >> 6;
    const int quad = lane >> 4;
    const int l15  = lane & 15;

    const int e = blockIdx.x * 256 + tid;
    const int d = dst[e];
    const int s = src[e];

    int slot = 0;
    if (msg32) slot = atomicAdd(cursor + d, 1);   // issue early, latency hides

    const uint4* pdrow = (const uint4*)(Pd + (size_t)d * 48);
    const uint4* psrow = (const uint4*)(Ps + (size_t)s * 16);

    // ---- edge MLP layer 1: h1 = relu(P1[d] + P2[s] + xe @ We1[64:70])
    float h1[32];
    #pragma unroll
    for (int i = 0; i < 4; ++i) {
        uint4 va = pdrow[i];
        uint4 vb = psrow[i];
        h1[8*i+0] = bflo(va.x) + bflo(vb.x);
        h1[8*i+1] = bfhi(va.x) + bfhi(vb.x);
        h1[8*i+2] = bflo(va.y) + bflo(vb.y);
        h1[8*i+3] = bfhi(va.y) + bfhi(vb.y);
        h1[8*i+4] = bflo(va.z) + bflo(vb.z);
        h1[8*i+5] = bfhi(va.z) + bfhi(vb.z);
        h1[8*i+6] = bflo(va.w) + bflo(vb.w);
        h1[8*i+7] = bfhi(va.w) + bfhi(vb.w);
    }
    float xe[6];
    {
        const float2* pe = (const float2*)(x_edge + (size_t)e * 6);
        float2 a = pe[0], b = pe[1], c = pe[2];
        xe[0]=a.x; xe[1]=a.y; xe[2]=b.x; xe[3]=b.y; xe[4]=c.x; xe[5]=c.y;
    }
    #pragma unroll
    for (int k = 0; k < 6; ++k) {
        const float a = xe[k];
        const float* w = We1 + (64 + k) * 32;
        #pragma unroll
        for (int j = 0; j < 32; ++j) h1[j] = fmaf(a, w[j], h1[j]);
    }
    #pragma unroll
    for (int j = 0; j < 32; ++j) h1[j] = fmaxf(h1[j], 0.0f);

    // ---- edge MLP layer 2: em = relu(h1 @ We2 + be2)
    float em[6];
    #pragma unroll
    for (int j = 0; j < 6; ++j) em[j] = be2[j];
    for (int k = 0; k < 32; ++k) {
        const float a = h1[k];
        const float* w = We2 + k * 6;
        #pragma unroll
        for (int j = 0; j < 6; ++j) em[j] = fmaf(a, w[j], em[j]);
    }
    #pragma unroll
    for (int j = 0; j < 6; ++j) em[j] = fmaxf(em[j], 0.0f);

    {
        float2* eo = (float2*)(em_out + (size_t)e * 6);
        eo[0] = make_float2(em[0], em[1]);
        eo[1] = make_float2(em[2], em[3]);
        eo[2] = make_float2(em[4], em[5]);
    }

    // ---- node MLP layer 1: h2 = relu(P3[d] + em @ Wn1[32:38])
    float h2[64];
    #pragma unroll
    for (int i = 0; i < 8; ++i) {
        uint4 v = pdrow[4 + i];
        h2[8*i+0] = bflo(v.x); h2[8*i+1] = bfhi(v.x);
        h2[8*i+2] = bflo(v.y); h2[8*i+3] = bfhi(v.y);
        h2[8*i+4] = bflo(v.z); h2[8*i+5] = bfhi(v.z);
        h2[8*i+6] = bflo(v.w); h2[8*i+7] = bfhi(v.w);
    }
    #pragma unroll
    for (int k = 0; k < 6; ++k) {
        const float a = em[k];
        const float* w = Wn1 + (32 + k) * 64;
        #pragma unroll
        for (int j = 0; j < 64; ++j) h2[j] = fmaf(a, w[j], h2[j]);
    }

    // pack relu(h2) -> bf16, stage in this wave's LDS tile (row = lane)
    {
        uint4* row = (uint4*)&s_h2[wave][lane][0];
        #pragma unroll
        for (int i = 0; i < 8; ++i) {
            uint4 v;
            v.x = pack_bf2(fmaxf(h2[8*i+0],0.f), fmaxf(h2[8*i+1],0.f));
            v.y = pack_bf2(fmaxf(h2[8*i+2],0.f), fmaxf(h2[8*i+3],0.f));
            v.z = pack_bf2(fmaxf(h2[8*i+4],0.f), fmaxf(h2[8*i+5],0.f));
            v.w = pack_bf2(fmaxf(h2[8*i+6],0.f), fmaxf(h2[8*i+7],0.f));
            row[i] = v;
        }
    }
    __syncthreads();

    // ---- nm = h2 @ Wn2 via MFMA: M=64 edges, N=32 outs, K=64
    bf16x8 bfr[2][2];
    #pragma unroll
    for (int n = 0; n < 2; ++n)
        #pragma unroll
        for (int kt = 0; kt < 2; ++kt)
            bfr[n][kt] = *(const bf16x8*)(Wn2T + (n*16 + l15)*64 + kt*32 + quad*8);

    f32x4 acc[4][2];
    #pragma unroll
    for (int m = 0; m < 4; ++m) { acc[m][0] = (f32x4)0.f; acc[m][1] = (f32x4)0.f; }

    #pragma unroll
    for (int m = 0; m < 4; ++m) {
        #pragma unroll
        for (int kt = 0; kt < 2; ++kt) {
            bf16x8 af = *(const bf16x8*)((const char*)&s_h2[wave][m*16 + l15][0]
                                         + kt*64 + quad*16);
            acc[m][0] = __builtin_amdgcn_mfma_f32_16x16x32_bf16(af, bfr[0][kt], acc[m][0], 0, 0, 0);
            acc[m][1] = __builtin_amdgcn_mfma_f32_16x16x32_bf16(af, bfr[1][kt], acc[m][1], 0, 0, 0);
        }
    }

    const float b0 = bn2[l15];
    const float b1 = bn2[16 + l15];

    if (msg32) {
        // ---- binned path: transpose C-layout via wave-private LDS, write bf16 row
        float* s_nm = (float*)&s_h2[wave][0][0];   // 64 x 33 f32 = 8448 B < 9216 B
        #pragma unroll
        for (int m = 0; m < 4; ++m)
            #pragma unroll
            for (int n = 0; n < 2; ++n) {
                const float bb = n ? b1 : b0;
                #pragma unroll
                for (int r = 0; r < 4; ++r)
                    s_nm[(m*16 + quad*4 + r)*33 + n*16 + l15] =
                        fmaxf(acc[m][n][r] + bb, 0.0f);
            }
        unsigned o[16];
        #pragma unroll
        for (int u = 0; u < 16; ++u)
            o[u] = pack_bf2(s_nm[lane*33 + 2*u], s_nm[lane*33 + 2*u + 1]);
        uint4* op = (uint4*)(msg32 + (size_t)slot * 16);
        op[0] = make_uint4(o[0],  o[1],  o[2],  o[3]);
        op[1] = make_uint4(o[4],  o[5],  o[6],  o[7]);
        op[2] = make_uint4(o[8],  o[9],  o[10], o[11]);
        op[3] = make_uint4(o[12], o[13], o[14], o[15]);
    } else {
        // ---- fallback: coalesced atomic segment-sum, 2 chunks of 128 edges
        float* s_nm = (float*)s_h2;
        #pragma unroll
        for (int chunk = 0; chunk < 2; ++chunk) {
            __syncthreads();
            if ((tid >> 7) == chunk) {
                s_dst[tid & 127] = d;
                const int be = (wave & 1) * 64;
                #pragma unroll
                for (int m = 0; m < 4; ++m) {
                    #pragma unroll
                    for (int n = 0; n < 2; ++n) {
                        const float bb = n ? b1 : b0;
                        #pragma unroll
                        for (int r = 0; r < 4; ++r) {
                            const int le  = be + m*16 + quad*4 + r;
                            const int out = n*16 + l15;
                            s_nm[le*33 + out] = fmaxf(acc[m][n][r] + bb, 0.0f);
                        }
                    }
                }
            }
            __syncthreads();
            #pragma unroll 4
            for (int it = 0; it < 16; ++it) {
                const int f  = it * 256 + tid;
                const int le = f >> 5;
                const int j  = f & 31;
                atomicAdd(nm_out + (size_t)s_dst[le] * 32 + j, s_nm[le*33 + j]);
            }
        }
    }
}

// ---------- pass 3: coalesced binned segment reduction ----------
__global__ void __launch_bounds__(256) mpn_reduce(
    const unsigned* __restrict__ msg32,   // [E][16] packed bf16x2, dst-binned
    const int* __restrict__ off,          // [N_NODES+1]
    float* __restrict__ nm_out)
{
    const int node = blockIdx.x * 4 + (threadIdx.x >> 6);
    if (node >= N_NODES) return;
    const int lane = threadIdx.x & 63;
    const int r4 = lane >> 4, u = lane & 15;
    const int b = off[node], e = off[node + 1];
    float a0 = 0.f, a1 = 0.f;
    for (int k = b + r4; k < e; k += 4) {
        const unsigned v = msg32[(size_t)k * 16 + u];
        a0 += bflo(v);
        a1 += bfhi(v);
    }
    a0 += __shfl_xor(a0, 16); a0 += __shfl_xor(a0, 32);
    a1 += __shfl_xor(a1, 16); a1 += __shfl_xor(a1, 32);
    if (lane < 16)
        *(float2*)(nm_out + (size_t)node * 32 + 2 * u) = make_float2(a0, a1);
}

extern "C" void kernel_launch(void* const* d_in, const int* in_sizes, int n_in,
                              void* d_out, int out_size, void* d_ws, size_t ws_size,
                              hipStream_t stream) {
    const float* x_node = (const float*)d_in[0];
    const float* x_edge = (const float*)d_in[1];
    const int*   src    = (const int*)d_in[2];
    const int*   dst    = (const int*)d_in[3];
    const float* We1 = (const float*)d_in[4];
    const float* be1 = (const float*)d_in[5];
    const float* We2 = (const float*)d_in[6];
    const float* be2 = (const float*)d_in[7];
    const float* Wn1 = (const float*)d_in[8];
    const float* bn1 = (const float*)d_in[9];
    const float* Wn2 = (const float*)d_in[10];
    const float* bn2 = (const float*)d_in[11];

    float* nm_out = (float*)d_out;                        // [N_NODES*32]
    float* em_out = (float*)d_out + (size_t)N_NODES * 32; // [N_EDGES*6]

    // workspace layout (bytes):
    //   Pd      @ 0          : 100000*48*4 = 19,200,000
    //   Ps      @ 19200000   : 100000*16*4 =  6,400,000
    //   Wn2T    @ 25600000   : 2048*2      =      4,096
    //   off     @ 25604096   : 100004*4    =    400,016
    //   cursor  @ 26004112   : 100000*4    =    400,000
    //   blksum  @ 26404112   : 128*4       =        512 (+pad)
    //   msg32   @ 26404864   : 3200000*64  = 204,800,000
    char* ws = (char*)d_ws;
    unsigned* Pd     = (unsigned*)ws;
    unsigned* Ps     = (unsigned*)(ws + 19200000);
    short*    Wn2T   = (short*)(ws + 25600000);
    int*      off    = (int*)(ws + 25604096);
    int*      cursor = (int*)(ws + 26004112);
    int*      blksum = (int*)(ws + 26404112);
    unsigned* msg32  = (unsigned*)(ws + 26404864);
    const size_t NEED = 26404864ULL + 204800000ULL;   // 231,204,864 B

    const bool binned = (ws_size >= NEED);
    const int NSCAN = (N_NODES + 1023) / 1024;        // 98

    mpn_precompute<<<(N_NODES + 255) / 256, 256, 0, stream>>>(
        x_node, We1, be1, Wn1, bn1, Wn2, Pd, Ps, Wn2T, nm_out,
        binned ? cursor : nullptr);

    if (binned) {
        k_hist  <<<N_EDGES / 256, 256, 0, stream>>>(dst, cursor);
        k_scan_a<<<NSCAN, 1024, 0, stream>>>(cursor, off, blksum);
        k_scan_b<<<1, 128, 0, stream>>>(blksum, NSCAN);
        k_scan_c<<<NSCAN, 1024, 0, stream>>>(off, cursor, blksum);
    }

    mpn_main<<<N_EDGES / 256, 256, 0, stream>>>(
        Pd, Ps, x_edge, src, dst,
        We1, We2, be2, Wn1, Wn2T, bn2,
        nm_out, em_out,
        binned ? msg32 : nullptr, binned ? cursor : nullptr);

    if (binned) {
        mpn_reduce<<<N_NODES / 4, 256, 0, stream>>>(msg32, off, nm_out);
    }
}